// Round 1
// baseline (3998.582 us; speedup 1.0000x reference)
//
#include <hip/hip_runtime.h>
#include <hip/hip_bf16.h>
#include <cstddef>

// Problem constants (fixed-shape problem)
constexpr int N_NODES = 50000;
constexpr int N_EDGES = 800000;
constexpr int IN_DIM  = 128;
constexpr int HID     = 64;
constexpr int HEADS   = 4;
constexpr int F1      = HEADS * HID;  // 256
constexpr int EMB     = 128;
constexpr int N_GRAPHS = 64;

__device__ __forceinline__ float lrelu(float x) { return x > 0.f ? x : 0.2f * x; }
__device__ __forceinline__ float eluf(float x)  { return x > 0.f ? x : expm1f(x); }

// ---------------------------------------------------------------------------
// Tiled f32 GEMM: C[M,N] = op(A)[M,K] @ B[K,N].  op = identity or ELU(a+bias[k]).
// BM=BN=64, BK=16, 256 threads, 4x4 micro-tile per thread.
// ---------------------------------------------------------------------------
template <bool ELU_A>
__global__ __launch_bounds__(256) void gemm_f32(const float* __restrict__ A,
                                                const float* __restrict__ B,
                                                const float* __restrict__ bias,
                                                float* __restrict__ C,
                                                int M, int N, int K) {
    constexpr int BM = 64, BN = 64, BK = 16;
    __shared__ float As[BK][BM + 4];  // [k][m], +4 pad: 2-way max bank alias (free)
    __shared__ float Bs[BK][BN];      // [k][n]

    const int tid = threadIdx.x;
    const int tx = tid & 15, ty = tid >> 4;
    const int m0 = blockIdx.y * BM, n0 = blockIdx.x * BN;

    // A-load: thread -> (row = tid/4, k-chunk = (tid%4)*4), float4 along K
    const int aRow = tid >> 2;
    const int aK   = (tid & 3) * 4;
    // B-load: thread -> (k = tid/16, n-chunk = (tid%16)*4), float4 along N
    const int bRow = tid >> 4;
    const int bCol = (tid & 15) * 4;

    float acc[4][4] = {};

    for (int kt = 0; kt < K; kt += BK) {
        float4 av = make_float4(0.f, 0.f, 0.f, 0.f);
        const int gm = m0 + aRow;
        if (gm < M) av = *(const float4*)&A[(size_t)gm * K + kt + aK];
        if (ELU_A) {
            av.x = eluf(av.x + bias[kt + aK + 0]);
            av.y = eluf(av.y + bias[kt + aK + 1]);
            av.z = eluf(av.z + bias[kt + aK + 2]);
            av.w = eluf(av.w + bias[kt + aK + 3]);
        }
        As[aK + 0][aRow] = av.x;
        As[aK + 1][aRow] = av.y;
        As[aK + 2][aRow] = av.z;
        As[aK + 3][aRow] = av.w;

        float4 bv = *(const float4*)&B[(size_t)(kt + bRow) * N + n0 + bCol];
        *(float4*)&Bs[bRow][bCol] = bv;

        __syncthreads();
#pragma unroll
        for (int k = 0; k < BK; k++) {
            float4 a4 = *(const float4*)&As[k][ty * 4];
            float4 b4 = *(const float4*)&Bs[k][tx * 4];
            acc[0][0] += a4.x * b4.x; acc[0][1] += a4.x * b4.y; acc[0][2] += a4.x * b4.z; acc[0][3] += a4.x * b4.w;
            acc[1][0] += a4.y * b4.x; acc[1][1] += a4.y * b4.y; acc[1][2] += a4.y * b4.z; acc[1][3] += a4.y * b4.w;
            acc[2][0] += a4.z * b4.x; acc[2][1] += a4.z * b4.y; acc[2][2] += a4.z * b4.z; acc[2][3] += a4.z * b4.w;
            acc[3][0] += a4.w * b4.x; acc[3][1] += a4.w * b4.y; acc[3][2] += a4.w * b4.z; acc[3][3] += a4.w * b4.w;
        }
        __syncthreads();
    }

#pragma unroll
    for (int i = 0; i < 4; i++) {
        const int gm = m0 + ty * 4 + i;
        if (gm < M) {
            float4 v = make_float4(acc[i][0], acc[i][1], acc[i][2], acc[i][3]);
            *(float4*)&C[(size_t)gm * N + n0 + tx * 4] = v;
        }
    }
}

// ---------------------------------------------------------------------------
// Layer-1 attention logits: wave per node. lane l covers channels 4l..4l+3
// (head = l>>4).  Reduce within each 16-lane head group.
// ---------------------------------------------------------------------------
__global__ __launch_bounds__(256) void alpha1_kernel(const float* __restrict__ h1,
                                                     const float* __restrict__ a_src,
                                                     const float* __restrict__ a_dst,
                                                     float* __restrict__ as1,
                                                     float* __restrict__ ad1, int N) {
    const int w = (blockIdx.x * 256 + threadIdx.x) >> 6;
    const int lane = threadIdx.x & 63;
    if (w >= N) return;
    const int head = lane >> 4;
    const int cc = (lane & 15) * 4;

    float4 hv = *(const float4*)&h1[(size_t)w * F1 + lane * 4];
    float4 sv = *(const float4*)&a_src[head * HID + cc];
    float4 dv = *(const float4*)&a_dst[head * HID + cc];
    float ps = hv.x * sv.x + hv.y * sv.y + hv.z * sv.z + hv.w * sv.w;
    float pd = hv.x * dv.x + hv.y * dv.y + hv.z * dv.z + hv.w * dv.w;
#pragma unroll
    for (int off = 1; off < 16; off <<= 1) {
        ps += __shfl_xor(ps, off);
        pd += __shfl_xor(pd, off);
    }
    if ((lane & 15) == 0) {
        as1[w * HEADS + head] = ps;
        ad1[w * HEADS + head] = pd;
    }
}

// Layer-2 attention logits (1 head, 128 ch): wave per node, float2 per lane.
__global__ __launch_bounds__(256) void alpha2_kernel(const float* __restrict__ g2,
                                                     const float* __restrict__ a_src,
                                                     const float* __restrict__ a_dst,
                                                     float* __restrict__ as2,
                                                     float* __restrict__ ad2, int N) {
    const int w = (blockIdx.x * 256 + threadIdx.x) >> 6;
    const int lane = threadIdx.x & 63;
    if (w >= N) return;
    float2 hv = *(const float2*)&g2[(size_t)w * EMB + lane * 2];
    float2 sv = *(const float2*)&a_src[lane * 2];
    float2 dv = *(const float2*)&a_dst[lane * 2];
    float ps = hv.x * sv.x + hv.y * sv.y;
    float pd = hv.x * dv.x + hv.y * dv.y;
#pragma unroll
    for (int off = 1; off < 64; off <<= 1) {
        ps += __shfl_xor(ps, off);
        pd += __shfl_xor(pd, off);
    }
    if (lane == 0) {
        as2[w] = ps;
        ad2[w] = pd;
    }
}

// ---------------------------------------------------------------------------
// Softmax denominators, layer 1: thread per edge (incl. implicit self-loops).
// ---------------------------------------------------------------------------
__global__ __launch_bounds__(256) void z1_kernel(const int* __restrict__ ei,
                                                 const float* __restrict__ as1,
                                                 const float* __restrict__ ad1,
                                                 float* __restrict__ z1, int E, int NE) {
    const int e = blockIdx.x * 256 + threadIdx.x;
    if (e >= NE) return;
    int s, d;
    if (e < E) { s = ei[e]; d = ei[E + e]; }
    else { s = d = e - E; }
    float4 a = *(const float4*)&as1[s * HEADS];
    float4 b = *(const float4*)&ad1[d * HEADS];
    atomicAdd(&z1[d * HEADS + 0], expf(lrelu(a.x + b.x)));
    atomicAdd(&z1[d * HEADS + 1], expf(lrelu(a.y + b.y)));
    atomicAdd(&z1[d * HEADS + 2], expf(lrelu(a.z + b.z)));
    atomicAdd(&z1[d * HEADS + 3], expf(lrelu(a.w + b.w)));
}

__global__ __launch_bounds__(256) void z2_kernel(const int* __restrict__ ei,
                                                 const float* __restrict__ as2,
                                                 const float* __restrict__ ad2,
                                                 float* __restrict__ z2, int E, int NE) {
    const int e = blockIdx.x * 256 + threadIdx.x;
    if (e >= NE) return;
    int s, d;
    if (e < E) { s = ei[e]; d = ei[E + e]; }
    else { s = d = e - E; }
    atomicAdd(&z2[d], expf(lrelu(as2[s] + ad2[d])));
}

// ---------------------------------------------------------------------------
// Message aggregation, layer 1: one wave per edge, float4 per lane (256 ch).
// ---------------------------------------------------------------------------
__global__ __launch_bounds__(256) void msg1_kernel(const int* __restrict__ ei,
                                                   const float* __restrict__ h1,
                                                   const float* __restrict__ as1,
                                                   const float* __restrict__ ad1,
                                                   const float* __restrict__ z1,
                                                   float* __restrict__ out1, int E, int NE) {
    const int w = (blockIdx.x * 256 + threadIdx.x) >> 6;
    const int lane = threadIdx.x & 63;
    if (w >= NE) return;
    int s, d;
    if (w < E) { s = ei[w]; d = ei[E + w]; }
    else { s = d = w - E; }
    const int head = lane >> 4;
    const float aa = as1[s * HEADS + head];
    const float bb = ad1[d * HEADS + head];
    const float zz = z1[d * HEADS + head];
    const float wgt = expf(lrelu(aa + bb)) / zz;
    float4 hv = *(const float4*)&h1[(size_t)s * F1 + lane * 4];
    float* op = &out1[(size_t)d * F1 + lane * 4];
    atomicAdd(op + 0, hv.x * wgt);
    atomicAdd(op + 1, hv.y * wgt);
    atomicAdd(op + 2, hv.z * wgt);
    atomicAdd(op + 3, hv.w * wgt);
}

// Message aggregation, layer 2: one wave per edge, float2 per lane (128 ch).
__global__ __launch_bounds__(256) void msg2_kernel(const int* __restrict__ ei,
                                                   const float* __restrict__ g2,
                                                   const float* __restrict__ as2,
                                                   const float* __restrict__ ad2,
                                                   const float* __restrict__ z2,
                                                   float* __restrict__ out2, int E, int NE) {
    const int w = (blockIdx.x * 256 + threadIdx.x) >> 6;
    const int lane = threadIdx.x & 63;
    if (w >= NE) return;
    int s, d;
    if (w < E) { s = ei[w]; d = ei[E + w]; }
    else { s = d = w - E; }
    const float wgt = expf(lrelu(as2[s] + ad2[d])) / z2[d];
    float2 hv = *(const float2*)&g2[(size_t)s * EMB + lane * 2];
    float* op = &out2[(size_t)d * EMB + lane * 2];
    atomicAdd(op + 0, hv.x * wgt);
    atomicAdd(op + 1, hv.y * wgt);
}

// ---------------------------------------------------------------------------
// Global mean pool: batch_vec is sorted, so per-block run-length accumulation
// with a flush on graph change keeps atomics rare. 128 threads (= channels),
// 64 nodes per block. Also accumulates per-graph node counts (thread 0).
// ---------------------------------------------------------------------------
__global__ __launch_bounds__(128) void pool_kernel(const float* __restrict__ out2,
                                                   const float* __restrict__ b2,
                                                   const int* __restrict__ batch,
                                                   float* __restrict__ pool,
                                                   float* __restrict__ cnt, int N) {
    const int c = threadIdx.x;  // 0..127
    const int n0 = blockIdx.x * 64;
    const int nend = min(n0 + 64, N);
    const float bias = b2[c];
    float acc = 0.f, cacc = 0.f;
    int curg = batch[n0];
    for (int n = n0; n < nend; n++) {
        const int g = batch[n];
        if (g != curg) {
            atomicAdd(&pool[curg * EMB + c], acc);
            if (c == 0) atomicAdd(&cnt[curg], cacc);
            acc = 0.f; cacc = 0.f; curg = g;
        }
        float v = out2[(size_t)n * EMB + c] + bias;
        v = v > 0.f ? v : expm1f(v);
        acc += v;
        cacc += 1.f;
    }
    atomicAdd(&pool[curg * EMB + c], acc);
    if (c == 0) atomicAdd(&cnt[curg], cacc);
}

__global__ __launch_bounds__(256) void div_kernel(const float* __restrict__ pool,
                                                  const float* __restrict__ cnt,
                                                  float* __restrict__ out) {
    const int i = blockIdx.x * 256 + threadIdx.x;  // 8192
    out[i] = pool[i] / fmaxf(cnt[i >> 7], 1.f);
}

// ---------------------------------------------------------------------------
extern "C" void kernel_launch(void* const* d_in, const int* in_sizes, int n_in,
                              void* d_out, int out_size, void* d_ws, size_t ws_size,
                              hipStream_t stream) {
    const float* x      = (const float*)d_in[0];
    const int*   ei     = (const int*)d_in[1];
    // d_in[2] edge_weight: unused by the reference
    const int*   batch  = (const int*)d_in[3];
    const float* W1     = (const float*)d_in[4];
    const float* a_src1 = (const float*)d_in[5];
    const float* a_dst1 = (const float*)d_in[6];
    const float* b1     = (const float*)d_in[7];
    const float* W2     = (const float*)d_in[8];
    const float* a_src2 = (const float*)d_in[9];
    const float* a_dst2 = (const float*)d_in[10];
    const float* b2     = (const float*)d_in[11];
    float* out = (float*)d_out;

    const int N = N_NODES, E = N_EDGES, NE = N_EDGES + N_NODES;

    // Workspace layout (floats). Zero-init region first -> single memset.
    float* ws   = (float*)d_ws;
    float* out1 = ws;                               // N*F1
    float* z1   = out1 + (size_t)N * F1;            // N*4
    float* out2 = z1 + (size_t)N * HEADS;           // N*EMB
    float* z2   = out2 + (size_t)N * EMB;           // N
    float* pool = z2 + N;                           // 64*128
    float* cnt  = pool + N_GRAPHS * EMB;            // 64
    const size_t zero_floats =
        (size_t)N * F1 + (size_t)N * HEADS + (size_t)N * EMB + N + N_GRAPHS * EMB + N_GRAPHS;
    float* h1  = cnt + N_GRAPHS;                    // N*F1
    float* as1 = h1 + (size_t)N * F1;               // N*4
    float* ad1 = as1 + (size_t)N * HEADS;           // N*4
    float* g2  = ad1 + (size_t)N * HEADS;           // N*EMB
    float* as2 = g2 + (size_t)N * EMB;              // N
    float* ad2 = as2 + N;                           // N

    hipMemsetAsync(ws, 0, zero_floats * sizeof(float), stream);

    // Layer 1
    gemm_f32<false><<<dim3(F1 / 64, (N + 63) / 64), 256, 0, stream>>>(x, W1, nullptr, h1, N, F1, IN_DIM);
    alpha1_kernel<<<(N + 3) / 4, 256, 0, stream>>>(h1, a_src1, a_dst1, as1, ad1, N);
    z1_kernel<<<(NE + 255) / 256, 256, 0, stream>>>(ei, as1, ad1, z1, E, NE);
    msg1_kernel<<<(NE + 3) / 4, 256, 0, stream>>>(ei, h1, as1, ad1, z1, out1, E, NE);

    // Layer 2 (ELU(out1 + b1) fused into GEMM2's A-operand load)
    gemm_f32<true><<<dim3(EMB / 64, (N + 63) / 64), 256, 0, stream>>>(out1, W2, b1, g2, N, EMB, F1);
    alpha2_kernel<<<(N + 3) / 4, 256, 0, stream>>>(g2, a_src2, a_dst2, as2, ad2, N);
    z2_kernel<<<(NE + 255) / 256, 256, 0, stream>>>(ei, as2, ad2, z2, E, NE);
    msg2_kernel<<<(NE + 3) / 4, 256, 0, stream>>>(ei, g2, as2, ad2, z2, out2, E, NE);

    // Pool + divide
    pool_kernel<<<(N + 63) / 64, 128, 0, stream>>>(out2, b2, batch, pool, cnt, N);
    div_kernel<<<(N_GRAPHS * EMB) / 256, 256, 0, stream>>>(pool, cnt, out);
}

// Round 2
// 661.805 us; speedup vs baseline: 6.0419x; 6.0419x over previous
//
#include <hip/hip_runtime.h>
#include <hip/hip_bf16.h>
#include <cstddef>

// Problem constants (fixed-shape problem)
constexpr int N_NODES = 50000;
constexpr int N_EDGES = 800000;
constexpr int IN_DIM  = 128;
constexpr int HID     = 64;
constexpr int HEADS   = 4;
constexpr int F1      = HEADS * HID;  // 256
constexpr int EMB     = 128;
constexpr int N_GRAPHS = 64;

__device__ __forceinline__ float lrelu(float x) { return x > 0.f ? x : 0.2f * x; }
__device__ __forceinline__ float eluf(float x)  { return x > 0.f ? x : expm1f(x); }

// ---------------------------------------------------------------------------
// Tiled f32 GEMM: C[M,N] = op(A)[M,K] @ B[K,N].  op = identity or ELU(a+bias[k]).
// BM=BN=64, BK=16, 256 threads, 4x4 micro-tile per thread.
// ---------------------------------------------------------------------------
template <bool ELU_A>
__global__ __launch_bounds__(256) void gemm_f32(const float* __restrict__ A,
                                                const float* __restrict__ B,
                                                const float* __restrict__ bias,
                                                float* __restrict__ C,
                                                int M, int N, int K) {
    constexpr int BM = 64, BN = 64, BK = 16;
    __shared__ float As[BK][BM + 4];
    __shared__ float Bs[BK][BN];

    const int tid = threadIdx.x;
    const int tx = tid & 15, ty = tid >> 4;
    const int m0 = blockIdx.y * BM, n0 = blockIdx.x * BN;

    const int aRow = tid >> 2;
    const int aK   = (tid & 3) * 4;
    const int bRow = tid >> 4;
    const int bCol = (tid & 15) * 4;

    float acc[4][4] = {};

    for (int kt = 0; kt < K; kt += BK) {
        float4 av = make_float4(0.f, 0.f, 0.f, 0.f);
        const int gm = m0 + aRow;
        if (gm < M) av = *(const float4*)&A[(size_t)gm * K + kt + aK];
        if (ELU_A) {
            av.x = eluf(av.x + bias[kt + aK + 0]);
            av.y = eluf(av.y + bias[kt + aK + 1]);
            av.z = eluf(av.z + bias[kt + aK + 2]);
            av.w = eluf(av.w + bias[kt + aK + 3]);
        }
        As[aK + 0][aRow] = av.x;
        As[aK + 1][aRow] = av.y;
        As[aK + 2][aRow] = av.z;
        As[aK + 3][aRow] = av.w;

        float4 bv = *(const float4*)&B[(size_t)(kt + bRow) * N + n0 + bCol];
        *(float4*)&Bs[bRow][bCol] = bv;

        __syncthreads();
#pragma unroll
        for (int k = 0; k < BK; k++) {
            float4 a4 = *(const float4*)&As[k][ty * 4];
            float4 b4 = *(const float4*)&Bs[k][tx * 4];
            acc[0][0] += a4.x * b4.x; acc[0][1] += a4.x * b4.y; acc[0][2] += a4.x * b4.z; acc[0][3] += a4.x * b4.w;
            acc[1][0] += a4.y * b4.x; acc[1][1] += a4.y * b4.y; acc[1][2] += a4.y * b4.z; acc[1][3] += a4.y * b4.w;
            acc[2][0] += a4.z * b4.x; acc[2][1] += a4.z * b4.y; acc[2][2] += a4.z * b4.z; acc[2][3] += a4.z * b4.w;
            acc[3][0] += a4.w * b4.x; acc[3][1] += a4.w * b4.y; acc[3][2] += a4.w * b4.z; acc[3][3] += a4.w * b4.w;
        }
        __syncthreads();
    }

#pragma unroll
    for (int i = 0; i < 4; i++) {
        const int gm = m0 + ty * 4 + i;
        if (gm < M) {
            float4 v = make_float4(acc[i][0], acc[i][1], acc[i][2], acc[i][3]);
            *(float4*)&C[(size_t)gm * N + n0 + tx * 4] = v;
        }
    }
}

// ---------------------------------------------------------------------------
// Attention logit kernels (unchanged from R1 — tiny cost).
// ---------------------------------------------------------------------------
__global__ __launch_bounds__(256) void alpha1_kernel(const float* __restrict__ h1,
                                                     const float* __restrict__ a_src,
                                                     const float* __restrict__ a_dst,
                                                     float* __restrict__ as1,
                                                     float* __restrict__ ad1, int N) {
    const int w = (blockIdx.x * 256 + threadIdx.x) >> 6;
    const int lane = threadIdx.x & 63;
    if (w >= N) return;
    const int head = lane >> 4;
    const int cc = (lane & 15) * 4;

    float4 hv = *(const float4*)&h1[(size_t)w * F1 + lane * 4];
    float4 sv = *(const float4*)&a_src[head * HID + cc];
    float4 dv = *(const float4*)&a_dst[head * HID + cc];
    float ps = hv.x * sv.x + hv.y * sv.y + hv.z * sv.z + hv.w * sv.w;
    float pd = hv.x * dv.x + hv.y * dv.y + hv.z * dv.z + hv.w * dv.w;
#pragma unroll
    for (int off = 1; off < 16; off <<= 1) {
        ps += __shfl_xor(ps, off);
        pd += __shfl_xor(pd, off);
    }
    if ((lane & 15) == 0) {
        as1[w * HEADS + head] = ps;
        ad1[w * HEADS + head] = pd;
    }
}

__global__ __launch_bounds__(256) void alpha2_kernel(const float* __restrict__ g2,
                                                     const float* __restrict__ a_src,
                                                     const float* __restrict__ a_dst,
                                                     float* __restrict__ as2,
                                                     float* __restrict__ ad2, int N) {
    const int w = (blockIdx.x * 256 + threadIdx.x) >> 6;
    const int lane = threadIdx.x & 63;
    if (w >= N) return;
    float2 hv = *(const float2*)&g2[(size_t)w * EMB + lane * 2];
    float2 sv = *(const float2*)&a_src[lane * 2];
    float2 dv = *(const float2*)&a_dst[lane * 2];
    float ps = hv.x * sv.x + hv.y * sv.y;
    float pd = hv.x * dv.x + hv.y * dv.y;
#pragma unroll
    for (int off = 1; off < 64; off <<= 1) {
        ps += __shfl_xor(ps, off);
        pd += __shfl_xor(pd, off);
    }
    if (lane == 0) {
        as2[w] = ps;
        ad2[w] = pd;
    }
}

// ---------------------------------------------------------------------------
// CSR build: degree histogram -> single-block scan -> scatter (src per slot).
// Self-loops are NOT stored; the aggregation kernels add them explicitly.
// ---------------------------------------------------------------------------
__global__ __launch_bounds__(256) void deg_kernel(const int* __restrict__ ei,
                                                  int* __restrict__ deg, int E) {
    const int e = blockIdx.x * 256 + threadIdx.x;
    if (e >= E) return;
    atomicAdd(&deg[ei[E + e]], 1);
}

__global__ __launch_bounds__(1024) void scan_kernel(const int* __restrict__ deg,
                                                    int* __restrict__ off, int N) {
    __shared__ int sums[1024];
    const int t = threadIdx.x;
    const int chunk = (N + 1023) / 1024;
    const int begin = t * chunk;
    const int end = min(begin + chunk, N);
    int s = 0;
    for (int i = begin; i < end; i++) s += deg[i];
    sums[t] = s;
    __syncthreads();
    for (int o = 1; o < 1024; o <<= 1) {
        int v = (t >= o) ? sums[t - o] : 0;
        __syncthreads();
        sums[t] += v;
        __syncthreads();
    }
    int excl = (t == 0) ? 0 : sums[t - 1];
    for (int i = begin; i < end; i++) {
        off[i] = excl;
        excl += deg[i];
    }
    if (t == 1023) off[N] = sums[1023];
}

__global__ __launch_bounds__(256) void scatter_kernel(const int* __restrict__ ei,
                                                      const int* __restrict__ off,
                                                      int* __restrict__ cur,
                                                      int* __restrict__ col, int E) {
    const int e = blockIdx.x * 256 + threadIdx.x;
    if (e >= E) return;
    const int s = ei[e], d = ei[E + e];
    const int pos = atomicAdd(&cur[d], 1);
    col[off[d] + pos] = s;
}

// ---------------------------------------------------------------------------
// Layer-1 aggregation: one wave per dst node. Lane l -> channels 4l..4l+3,
// head = l>>4. Softmax denominator accumulated in the same pass (z), divide
// at the end. No atomics; out1[d] written exactly once.
// ---------------------------------------------------------------------------
__global__ __launch_bounds__(256) void agg1_kernel(const int* __restrict__ off,
                                                   const int* __restrict__ col,
                                                   const float* __restrict__ h1,
                                                   const float* __restrict__ as1,
                                                   const float* __restrict__ ad1,
                                                   float* __restrict__ out1, int N) {
    const int w = (blockIdx.x * 256 + threadIdx.x) >> 6;
    const int lane = threadIdx.x & 63;
    if (w >= N) return;
    const int head = lane >> 4;
    const float ad = ad1[w * HEADS + head];

    float4 acc = make_float4(0.f, 0.f, 0.f, 0.f);
    float z = 0.f;

    // self-loop
    {
        const float wt = expf(lrelu(as1[w * HEADS + head] + ad));
        float4 hv = *(const float4*)&h1[(size_t)w * F1 + lane * 4];
        acc.x += wt * hv.x; acc.y += wt * hv.y; acc.z += wt * hv.z; acc.w += wt * hv.w;
        z += wt;
    }
    const int jb = off[w], je = off[w + 1];
    int s = (jb < je) ? col[jb] : 0;
    for (int j = jb; j < je; j++) {
        const int sn = (j + 1 < je) ? col[j + 1] : 0;  // prefetch next src idx
        const float wt = expf(lrelu(as1[s * HEADS + head] + ad));
        float4 hv = *(const float4*)&h1[(size_t)s * F1 + lane * 4];
        acc.x += wt * hv.x; acc.y += wt * hv.y; acc.z += wt * hv.z; acc.w += wt * hv.w;
        z += wt;
        s = sn;
    }
    const float inv = 1.f / z;
    float4 o = make_float4(acc.x * inv, acc.y * inv, acc.z * inv, acc.w * inv);
    *(float4*)&out1[(size_t)w * F1 + lane * 4] = o;
}

// Layer-2 aggregation: one wave per dst node, float2 per lane (128 ch, 1 head).
__global__ __launch_bounds__(256) void agg2_kernel(const int* __restrict__ off,
                                                   const int* __restrict__ col,
                                                   const float* __restrict__ g2,
                                                   const float* __restrict__ as2,
                                                   const float* __restrict__ ad2,
                                                   float* __restrict__ out2, int N) {
    const int w = (blockIdx.x * 256 + threadIdx.x) >> 6;
    const int lane = threadIdx.x & 63;
    if (w >= N) return;
    const float ad = ad2[w];

    float2 acc = make_float2(0.f, 0.f);
    float z = 0.f;
    {
        const float wt = expf(lrelu(as2[w] + ad));
        float2 hv = *(const float2*)&g2[(size_t)w * EMB + lane * 2];
        acc.x += wt * hv.x; acc.y += wt * hv.y;
        z += wt;
    }
    const int jb = off[w], je = off[w + 1];
    int s = (jb < je) ? col[jb] : 0;
    for (int j = jb; j < je; j++) {
        const int sn = (j + 1 < je) ? col[j + 1] : 0;
        const float wt = expf(lrelu(as2[s] + ad));
        float2 hv = *(const float2*)&g2[(size_t)s * EMB + lane * 2];
        acc.x += wt * hv.x; acc.y += wt * hv.y;
        z += wt;
        s = sn;
    }
    const float inv = 1.f / z;
    float2 o = make_float2(acc.x * inv, acc.y * inv);
    *(float2*)&out2[(size_t)w * EMB + lane * 2] = o;
}

// ---------------------------------------------------------------------------
// Global mean pool (batch_vec sorted -> run-length accumulate, rare atomics).
// ---------------------------------------------------------------------------
__global__ __launch_bounds__(128) void pool_kernel(const float* __restrict__ out2,
                                                   const float* __restrict__ b2,
                                                   const int* __restrict__ batch,
                                                   float* __restrict__ pool,
                                                   float* __restrict__ cnt, int N) {
    const int c = threadIdx.x;
    const int n0 = blockIdx.x * 64;
    const int nend = min(n0 + 64, N);
    const float bias = b2[c];
    float acc = 0.f, cacc = 0.f;
    int curg = batch[n0];
    for (int n = n0; n < nend; n++) {
        const int g = batch[n];
        if (g != curg) {
            atomicAdd(&pool[curg * EMB + c], acc);
            if (c == 0) atomicAdd(&cnt[curg], cacc);
            acc = 0.f; cacc = 0.f; curg = g;
        }
        float v = out2[(size_t)n * EMB + c] + bias;
        v = v > 0.f ? v : expm1f(v);
        acc += v;
        cacc += 1.f;
    }
    atomicAdd(&pool[curg * EMB + c], acc);
    if (c == 0) atomicAdd(&cnt[curg], cacc);
}

__global__ __launch_bounds__(256) void div_kernel(const float* __restrict__ pool,
                                                  const float* __restrict__ cnt,
                                                  float* __restrict__ out) {
    const int i = blockIdx.x * 256 + threadIdx.x;
    out[i] = pool[i] / fmaxf(cnt[i >> 7], 1.f);
}

// ---------------------------------------------------------------------------
extern "C" void kernel_launch(void* const* d_in, const int* in_sizes, int n_in,
                              void* d_out, int out_size, void* d_ws, size_t ws_size,
                              hipStream_t stream) {
    const float* x      = (const float*)d_in[0];
    const int*   ei     = (const int*)d_in[1];
    const int*   batch  = (const int*)d_in[3];
    const float* W1     = (const float*)d_in[4];
    const float* a_src1 = (const float*)d_in[5];
    const float* a_dst1 = (const float*)d_in[6];
    const float* b1     = (const float*)d_in[7];
    const float* W2     = (const float*)d_in[8];
    const float* a_src2 = (const float*)d_in[9];
    const float* a_dst2 = (const float*)d_in[10];
    const float* b2     = (const float*)d_in[11];
    float* out = (float*)d_out;

    const int N = N_NODES, E = N_EDGES;

    // Workspace layout. Zero-init region first -> single small memset.
    char* p = (char*)d_ws;
    int* deg   = (int*)p;                 p += (size_t)N * 4;
    int* cur   = (int*)p;                 p += (size_t)N * 4;
    float* pool= (float*)p;               p += (size_t)N_GRAPHS * EMB * 4;
    float* cnt = (float*)p;               p += (size_t)N_GRAPHS * 4;
    const size_t zero_bytes = (size_t)p - (size_t)d_ws;
    int* off   = (int*)p;                 p += (size_t)(N + 1) * 4;
    int* col   = (int*)p;                 p += (size_t)E * 4;
    float* h1  = (float*)p;               p += (size_t)N * F1 * 4;
    float* out1= (float*)p;               p += (size_t)N * F1 * 4;
    float* g2  = (float*)p;               p += (size_t)N * EMB * 4;
    float* out2= (float*)p;               p += (size_t)N * EMB * 4;
    float* as1 = (float*)p;               p += (size_t)N * HEADS * 4;
    float* ad1 = (float*)p;               p += (size_t)N * HEADS * 4;
    float* as2 = (float*)p;               p += (size_t)N * 4;
    float* ad2 = (float*)p;               p += (size_t)N * 4;

    hipMemsetAsync(d_ws, 0, zero_bytes, stream);

    // CSR build (dst -> srcs), self-loops handled in agg kernels
    deg_kernel<<<(E + 255) / 256, 256, 0, stream>>>(ei, deg, E);
    scan_kernel<<<1, 1024, 0, stream>>>(deg, off, N);
    scatter_kernel<<<(E + 255) / 256, 256, 0, stream>>>(ei, off, cur, col, E);

    // Layer 1
    gemm_f32<false><<<dim3(F1 / 64, (N + 63) / 64), 256, 0, stream>>>(x, W1, nullptr, h1, N, F1, IN_DIM);
    alpha1_kernel<<<(N + 3) / 4, 256, 0, stream>>>(h1, a_src1, a_dst1, as1, ad1, N);
    agg1_kernel<<<(N + 3) / 4, 256, 0, stream>>>(off, col, h1, as1, ad1, out1, N);

    // Layer 2 (ELU(out1 + b1) fused into GEMM2's A-operand load)
    gemm_f32<true><<<dim3(EMB / 64, (N + 63) / 64), 256, 0, stream>>>(out1, W2, b1, g2, N, EMB, F1);
    alpha2_kernel<<<(N + 3) / 4, 256, 0, stream>>>(g2, a_src2, a_dst2, as2, ad2, N);
    agg2_kernel<<<(N + 3) / 4, 256, 0, stream>>>(off, col, g2, as2, ad2, out2, N);

    // Pool + divide
    pool_kernel<<<(N + 63) / 64, 128, 0, stream>>>(out2, b2, batch, pool, cnt, N);
    div_kernel<<<(N_GRAPHS * EMB) / 256, 256, 0, stream>>>(pool, cnt, out);
}

// Round 3
// 608.123 us; speedup vs baseline: 6.5753x; 1.0883x over previous
//
#include <hip/hip_runtime.h>
#include <hip/hip_bf16.h>
#include <cstddef>

// Problem constants (fixed-shape problem)
constexpr int N_NODES = 50000;
constexpr int N_EDGES = 800000;
constexpr int IN_DIM  = 128;
constexpr int HID     = 64;
constexpr int HEADS   = 4;
constexpr int F1      = HEADS * HID;  // 256
constexpr int EMB     = 128;
constexpr int N_GRAPHS = 64;

typedef __bf16 bf16x8 __attribute__((ext_vector_type(8)));
typedef float  f32x4  __attribute__((ext_vector_type(4)));

__device__ __forceinline__ float lrelu(float x) { return x > 0.f ? x : 0.2f * x; }
__device__ __forceinline__ float eluf(float x)  { return x > 0.f ? x : expm1f(x); }

// ---------------------------------------------------------------------------
// Pack B [K x Ncols] f32 into per-lane MFMA B-fragments, split hi/lo bf16.
// Fragment layout for mfma_f32_16x16x32_bf16 B-operand:
//   lane -> n = t*16 + (lane&15), k = kk*32 + (lane>>4)*8 + j   (j = 0..7)
// Flat pack index: (((t*KK + kk)*64 + lane)*8 + j)  -> 16B-contiguous per lane.
// ---------------------------------------------------------------------------
__global__ __launch_bounds__(256) void pack_b(const float* __restrict__ B,
                                              __bf16* __restrict__ hi,
                                              __bf16* __restrict__ lo,
                                              int NT, int KK, int Ncols) {
    const int gid = blockIdx.x * 256 + threadIdx.x;
    if (gid >= NT * KK * 64) return;
    const int lane = gid & 63;
    const int rem  = gid >> 6;        // t*KK + kk
    const int kk   = rem % KK;
    const int t    = rem / KK;
    const int n    = t * 16 + (lane & 15);
    const int k0   = kk * 32 + (lane >> 4) * 8;
#pragma unroll
    for (int j = 0; j < 8; j++) {
        const float v = B[(size_t)(k0 + j) * Ncols + n];
        const __bf16 h = (__bf16)v;
        hi[(size_t)gid * 8 + j] = h;
        lo[(size_t)gid * 8 + j] = (__bf16)(v - (float)h);
    }
}

// ---------------------------------------------------------------------------
// Split-bf16 MFMA GEMM: C[M, NT*16] = op(A)[M, KK*32] @ B.
// D = Ahi*Bhi + Alo*Bhi + Ahi*Blo  (drops only lo*lo, ~1e-5 rel error).
// 256 threads = 4 waves; wave w owns rows [blk*64 + w*16, +16).
// A loaded from global f32 and split in registers (no LDS).
// op = identity or ELU(a + bias[k]) (fused layer-2 activation).
// ---------------------------------------------------------------------------
template <int NT, int KK, bool ELU_A>
__global__ __launch_bounds__(256) void gemm_mfma(const float* __restrict__ A,
                                                 const __bf16* __restrict__ Bh,
                                                 const __bf16* __restrict__ Bl,
                                                 const float* __restrict__ bias,
                                                 float* __restrict__ C, int M) {
    constexpr int Ncols = NT * 16;
    constexpr int K = KK * 32;
    const int tid  = threadIdx.x;
    const int wave = tid >> 6, lane = tid & 63;
    const int quad = lane >> 4, l16 = lane & 15;
    // A-operand row for this lane (m = lane&15), clamped for the ragged tail.
    const int rowA = min(blockIdx.x * 64 + wave * 16 + l16, M - 1);

    f32x4 acc[NT];
#pragma unroll
    for (int t = 0; t < NT; t++) acc[t] = (f32x4){0.f, 0.f, 0.f, 0.f};

    for (int kk = 0; kk < KK; kk++) {
        const int k0 = kk * 32 + quad * 8;
        float a8[8];
        *(float4*)&a8[0] = *(const float4*)&A[(size_t)rowA * K + k0];
        *(float4*)&a8[4] = *(const float4*)&A[(size_t)rowA * K + k0 + 4];
        if (ELU_A) {
#pragma unroll
            for (int j = 0; j < 8; j++) a8[j] = eluf(a8[j] + bias[k0 + j]);
        }
        bf16x8 ah, al;
#pragma unroll
        for (int j = 0; j < 8; j++) {
            const __bf16 h = (__bf16)a8[j];
            ah[j] = h;
            al[j] = (__bf16)(a8[j] - (float)h);
        }
#pragma unroll
        for (int t = 0; t < NT; t++) {
            const size_t bi = ((size_t)(t * KK + kk) * 64 + lane) * 8;
            bf16x8 bhv = *(const bf16x8*)&Bh[bi];
            bf16x8 blv = *(const bf16x8*)&Bl[bi];
            acc[t] = __builtin_amdgcn_mfma_f32_16x16x32_bf16(ah, bhv, acc[t], 0, 0, 0);
            acc[t] = __builtin_amdgcn_mfma_f32_16x16x32_bf16(al, bhv, acc[t], 0, 0, 0);
            acc[t] = __builtin_amdgcn_mfma_f32_16x16x32_bf16(ah, blv, acc[t], 0, 0, 0);
        }
    }

    // C/D layout: col = t*16 + (lane&15), row = quad*4 + reg (within wave tile)
    const int rowS = blockIdx.x * 64 + wave * 16 + quad * 4;
#pragma unroll
    for (int t = 0; t < NT; t++) {
#pragma unroll
        for (int r = 0; r < 4; r++) {
            const int rr = rowS + r;
            if (rr < M) C[(size_t)rr * Ncols + t * 16 + l16] = acc[t][r];
        }
    }
}

// ---------------------------------------------------------------------------
// Attention logit kernels.
// ---------------------------------------------------------------------------
__global__ __launch_bounds__(256) void alpha1_kernel(const float* __restrict__ h1,
                                                     const float* __restrict__ a_src,
                                                     const float* __restrict__ a_dst,
                                                     float* __restrict__ as1,
                                                     float* __restrict__ ad1, int N) {
    const int w = (blockIdx.x * 256 + threadIdx.x) >> 6;
    const int lane = threadIdx.x & 63;
    if (w >= N) return;
    const int head = lane >> 4;
    const int cc = (lane & 15) * 4;

    float4 hv = *(const float4*)&h1[(size_t)w * F1 + lane * 4];
    float4 sv = *(const float4*)&a_src[head * HID + cc];
    float4 dv = *(const float4*)&a_dst[head * HID + cc];
    float ps = hv.x * sv.x + hv.y * sv.y + hv.z * sv.z + hv.w * sv.w;
    float pd = hv.x * dv.x + hv.y * dv.y + hv.z * dv.z + hv.w * dv.w;
#pragma unroll
    for (int off = 1; off < 16; off <<= 1) {
        ps += __shfl_xor(ps, off);
        pd += __shfl_xor(pd, off);
    }
    if ((lane & 15) == 0) {
        as1[w * HEADS + head] = ps;
        ad1[w * HEADS + head] = pd;
    }
}

__global__ __launch_bounds__(256) void alpha2_kernel(const float* __restrict__ g2,
                                                     const float* __restrict__ a_src,
                                                     const float* __restrict__ a_dst,
                                                     float* __restrict__ as2,
                                                     float* __restrict__ ad2, int N) {
    const int w = (blockIdx.x * 256 + threadIdx.x) >> 6;
    const int lane = threadIdx.x & 63;
    if (w >= N) return;
    float2 hv = *(const float2*)&g2[(size_t)w * EMB + lane * 2];
    float2 sv = *(const float2*)&a_src[lane * 2];
    float2 dv = *(const float2*)&a_dst[lane * 2];
    float ps = hv.x * sv.x + hv.y * sv.y;
    float pd = hv.x * dv.x + hv.y * dv.y;
#pragma unroll
    for (int off = 1; off < 64; off <<= 1) {
        ps += __shfl_xor(ps, off);
        pd += __shfl_xor(pd, off);
    }
    if (lane == 0) {
        as2[w] = ps;
        ad2[w] = pd;
    }
}

// ---------------------------------------------------------------------------
// CSR build (dst -> srcs). Self-loops handled in agg kernels.
// ---------------------------------------------------------------------------
__global__ __launch_bounds__(256) void deg_kernel(const int* __restrict__ ei,
                                                  int* __restrict__ deg, int E) {
    const int e = blockIdx.x * 256 + threadIdx.x;
    if (e >= E) return;
    atomicAdd(&deg[ei[E + e]], 1);
}

__global__ __launch_bounds__(1024) void scan_kernel(const int* __restrict__ deg,
                                                    int* __restrict__ off, int N) {
    __shared__ int sums[1024];
    const int t = threadIdx.x;
    const int chunk = (N + 1023) / 1024;
    const int begin = t * chunk;
    const int end = min(begin + chunk, N);
    int s = 0;
    for (int i = begin; i < end; i++) s += deg[i];
    sums[t] = s;
    __syncthreads();
    for (int o = 1; o < 1024; o <<= 1) {
        int v = (t >= o) ? sums[t - o] : 0;
        __syncthreads();
        sums[t] += v;
        __syncthreads();
    }
    int excl = (t == 0) ? 0 : sums[t - 1];
    for (int i = begin; i < end; i++) {
        off[i] = excl;
        excl += deg[i];
    }
    if (t == 1023) off[N] = sums[1023];
}

__global__ __launch_bounds__(256) void scatter_kernel(const int* __restrict__ ei,
                                                      const int* __restrict__ off,
                                                      int* __restrict__ cur,
                                                      int* __restrict__ col, int E) {
    const int e = blockIdx.x * 256 + threadIdx.x;
    if (e >= E) return;
    const int s = ei[e], d = ei[E + e];
    const int pos = atomicAdd(&cur[d], 1);
    col[off[d] + pos] = s;
}

// ---------------------------------------------------------------------------
// Layer-1 aggregation: one wave per dst node (see R2 notes).
// ---------------------------------------------------------------------------
__global__ __launch_bounds__(256) void agg1_kernel(const int* __restrict__ off,
                                                   const int* __restrict__ col,
                                                   const float* __restrict__ h1,
                                                   const float* __restrict__ as1,
                                                   const float* __restrict__ ad1,
                                                   float* __restrict__ out1, int N) {
    const int w = (blockIdx.x * 256 + threadIdx.x) >> 6;
    const int lane = threadIdx.x & 63;
    if (w >= N) return;
    const int head = lane >> 4;
    const float ad = ad1[w * HEADS + head];

    float4 acc = make_float4(0.f, 0.f, 0.f, 0.f);
    float z = 0.f;
    {
        const float wt = expf(lrelu(as1[w * HEADS + head] + ad));
        float4 hv = *(const float4*)&h1[(size_t)w * F1 + lane * 4];
        acc.x += wt * hv.x; acc.y += wt * hv.y; acc.z += wt * hv.z; acc.w += wt * hv.w;
        z += wt;
    }
    const int jb = off[w], je = off[w + 1];
    int s = (jb < je) ? col[jb] : 0;
    for (int j = jb; j < je; j++) {
        const int sn = (j + 1 < je) ? col[j + 1] : 0;
        const float wt = expf(lrelu(as1[s * HEADS + head] + ad));
        float4 hv = *(const float4*)&h1[(size_t)s * F1 + lane * 4];
        acc.x += wt * hv.x; acc.y += wt * hv.y; acc.z += wt * hv.z; acc.w += wt * hv.w;
        z += wt;
        s = sn;
    }
    const float inv = 1.f / z;
    float4 o = make_float4(acc.x * inv, acc.y * inv, acc.z * inv, acc.w * inv);
    *(float4*)&out1[(size_t)w * F1 + lane * 4] = o;
}

__global__ __launch_bounds__(256) void agg2_kernel(const int* __restrict__ off,
                                                   const int* __restrict__ col,
                                                   const float* __restrict__ g2,
                                                   const float* __restrict__ as2,
                                                   const float* __restrict__ ad2,
                                                   float* __restrict__ out2, int N) {
    const int w = (blockIdx.x * 256 + threadIdx.x) >> 6;
    const int lane = threadIdx.x & 63;
    if (w >= N) return;
    const float ad = ad2[w];

    float2 acc = make_float2(0.f, 0.f);
    float z = 0.f;
    {
        const float wt = expf(lrelu(as2[w] + ad));
        float2 hv = *(const float2*)&g2[(size_t)w * EMB + lane * 2];
        acc.x += wt * hv.x; acc.y += wt * hv.y;
        z += wt;
    }
    const int jb = off[w], je = off[w + 1];
    int s = (jb < je) ? col[jb] : 0;
    for (int j = jb; j < je; j++) {
        const int sn = (j + 1 < je) ? col[j + 1] : 0;
        const float wt = expf(lrelu(as2[s] + ad));
        float2 hv = *(const float2*)&g2[(size_t)s * EMB + lane * 2];
        acc.x += wt * hv.x; acc.y += wt * hv.y;
        z += wt;
        s = sn;
    }
    const float inv = 1.f / z;
    float2 o = make_float2(acc.x * inv, acc.y * inv);
    *(float2*)&out2[(size_t)w * EMB + lane * 2] = o;
}

// ---------------------------------------------------------------------------
// Global mean pool + divide.
// ---------------------------------------------------------------------------
__global__ __launch_bounds__(128) void pool_kernel(const float* __restrict__ out2,
                                                   const float* __restrict__ b2,
                                                   const int* __restrict__ batch,
                                                   float* __restrict__ pool,
                                                   float* __restrict__ cnt, int N) {
    const int c = threadIdx.x;
    const int n0 = blockIdx.x * 64;
    const int nend = min(n0 + 64, N);
    const float bias = b2[c];
    float acc = 0.f, cacc = 0.f;
    int curg = batch[n0];
    for (int n = n0; n < nend; n++) {
        const int g = batch[n];
        if (g != curg) {
            atomicAdd(&pool[curg * EMB + c], acc);
            if (c == 0) atomicAdd(&cnt[curg], cacc);
            acc = 0.f; cacc = 0.f; curg = g;
        }
        float v = out2[(size_t)n * EMB + c] + bias;
        v = v > 0.f ? v : expm1f(v);
        acc += v;
        cacc += 1.f;
    }
    atomicAdd(&pool[curg * EMB + c], acc);
    if (c == 0) atomicAdd(&cnt[curg], cacc);
}

__global__ __launch_bounds__(256) void div_kernel(const float* __restrict__ pool,
                                                  const float* __restrict__ cnt,
                                                  float* __restrict__ out) {
    const int i = blockIdx.x * 256 + threadIdx.x;
    out[i] = pool[i] / fmaxf(cnt[i >> 7], 1.f);
}

// ---------------------------------------------------------------------------
extern "C" void kernel_launch(void* const* d_in, const int* in_sizes, int n_in,
                              void* d_out, int out_size, void* d_ws, size_t ws_size,
                              hipStream_t stream) {
    const float* x      = (const float*)d_in[0];
    const int*   ei     = (const int*)d_in[1];
    const int*   batch  = (const int*)d_in[3];
    const float* W1     = (const float*)d_in[4];
    const float* a_src1 = (const float*)d_in[5];
    const float* a_dst1 = (const float*)d_in[6];
    const float* b1     = (const float*)d_in[7];
    const float* W2     = (const float*)d_in[8];
    const float* a_src2 = (const float*)d_in[9];
    const float* a_dst2 = (const float*)d_in[10];
    const float* b2     = (const float*)d_in[11];
    float* out = (float*)d_out;

    const int N = N_NODES, E = N_EDGES;

    // Workspace carve, 256 B alignment per buffer (16 B vector loads need it).
    size_t cur_off = 0;
    auto carve = [&](size_t bytes) {
        size_t o = cur_off;
        cur_off = (cur_off + bytes + 255) & ~(size_t)255;
        return (char*)d_ws + o;
    };
    int* deg     = (int*)carve((size_t)N * 4);
    int* curp    = (int*)carve((size_t)N * 4);
    float* pool  = (float*)carve((size_t)N_GRAPHS * EMB * 4);
    float* cnt   = (float*)carve((size_t)N_GRAPHS * 4);
    const size_t zero_bytes = cur_off;  // everything above is zero-init
    __bf16* Bp1h = (__bf16*)carve((size_t)IN_DIM * F1 * 2);
    __bf16* Bp1l = (__bf16*)carve((size_t)IN_DIM * F1 * 2);
    __bf16* Bp2h = (__bf16*)carve((size_t)F1 * EMB * 2);
    __bf16* Bp2l = (__bf16*)carve((size_t)F1 * EMB * 2);
    int* off     = (int*)carve((size_t)(N + 1) * 4);
    int* col     = (int*)carve((size_t)E * 4);
    float* h1    = (float*)carve((size_t)N * F1 * 4);
    float* out1  = (float*)carve((size_t)N * F1 * 4);
    float* g2    = (float*)carve((size_t)N * EMB * 4);
    float* out2  = (float*)carve((size_t)N * EMB * 4);
    float* as1   = (float*)carve((size_t)N * HEADS * 4);
    float* ad1   = (float*)carve((size_t)N * HEADS * 4);
    float* as2   = (float*)carve((size_t)N * 4);
    float* ad2   = (float*)carve((size_t)N * 4);

    hipMemsetAsync(d_ws, 0, zero_bytes, stream);

    // CSR build
    deg_kernel<<<(E + 255) / 256, 256, 0, stream>>>(ei, deg, E);
    scan_kernel<<<1, 1024, 0, stream>>>(deg, off, N);
    scatter_kernel<<<(E + 255) / 256, 256, 0, stream>>>(ei, off, curp, col, E);

    // Weight packing (tiny)
    pack_b<<<16, 256, 0, stream>>>(W1, Bp1h, Bp1l, F1 / 16, IN_DIM / 32, F1);
    pack_b<<<16, 256, 0, stream>>>(W2, Bp2h, Bp2l, EMB / 16, F1 / 32, EMB);

    // Layer 1: h1 = x @ W1  (split-bf16 MFMA)
    gemm_mfma<F1 / 16, IN_DIM / 32, false>
        <<<(N + 63) / 64, 256, 0, stream>>>(x, Bp1h, Bp1l, nullptr, h1, N);
    alpha1_kernel<<<(N + 3) / 4, 256, 0, stream>>>(h1, a_src1, a_dst1, as1, ad1, N);
    agg1_kernel<<<(N + 3) / 4, 256, 0, stream>>>(off, col, h1, as1, ad1, out1, N);

    // Layer 2: g2 = ELU(out1 + b1) @ W2  (activation fused into A-split)
    gemm_mfma<EMB / 16, F1 / 32, true>
        <<<(N + 63) / 64, 256, 0, stream>>>(out1, Bp2h, Bp2l, b1, g2, N);
    alpha2_kernel<<<(N + 3) / 4, 256, 0, stream>>>(g2, a_src2, a_dst2, as2, ad2, N);
    agg2_kernel<<<(N + 3) / 4, 256, 0, stream>>>(off, col, g2, as2, ad2, out2, N);

    // Pool + divide
    pool_kernel<<<(N + 63) / 64, 128, 0, stream>>>(out2, b2, batch, pool, cnt, N);
    div_kernel<<<(N_GRAPHS * EMB) / 256, 256, 0, stream>>>(pool, cnt, out);
}